// Round 8
// baseline (255.879 us; speedup 1.0000x reference)
//
#include <hip/hip_runtime.h>
#include <hip/hip_bf16.h>

typedef __hip_bfloat16 bf16;
typedef __attribute__((ext_vector_type(4))) float f32x4;
typedef __attribute__((ext_vector_type(8))) short bf16x8;  // 8 bf16 in 4 VGPRs
typedef __attribute__((ext_vector_type(4))) short bf16x4;  // 4 bf16 in 2 VGPRs

// ---------------------------------------------------------------------------
// helpers
// ---------------------------------------------------------------------------
__device__ __forceinline__ void gload_lds16(const bf16* g, bf16* l) {
  __builtin_amdgcn_global_load_lds(
      (const __attribute__((address_space(1))) unsigned int*)(const void*)g,
      (__attribute__((address_space(3))) unsigned int*)(void*)l,
      16, 0, 0);
}

// XCD-contiguous bijective swizzle; REQUIRES nwg % 8 == 0.
__device__ __forceinline__ int xcd_swz(int orig, int nwg) {
  return (orig & 7) * (nwg >> 3) + (orig >> 3);
}

__device__ __forceinline__ float b2f(ushort u) {
  return __uint_as_float(((unsigned)u) << 16);
}

// 16x16x16 bf16 MFMA (K=16): A-frag = lane{row=l&15, k=(l>>4)*4+0..3}
#if defined(__has_builtin)
#if __has_builtin(__builtin_amdgcn_mfma_f32_16x16x16bf16_1k)
#define HAVE_MFMA16_BUILTIN 1
#endif
#endif
__device__ __forceinline__ f32x4 mfma16(bf16x4 a, bf16x4 b, f32x4 c) {
#ifdef HAVE_MFMA16_BUILTIN
  return __builtin_amdgcn_mfma_f32_16x16x16bf16_1k(a, b, c, 0, 0, 0);
#else
  asm("v_mfma_f32_16x16x16_bf16 %0, %1, %2, %0" : "+v"(c) : "v"(a), "v"(b));
  return c;
#endif
}

// ---------------------------------------------------------------------------
// fp32 -> bf16 conversion (vectorized, exact grid)
// ---------------------------------------------------------------------------
__global__ void cvt_f32_bf16(const float* __restrict__ in, bf16* __restrict__ out) {
  size_t i = ((size_t)blockIdx.x * 256 + threadIdx.x) * 4;
  float4 v = *reinterpret_cast<const float4*>(in + i);
  bf16 o[4] = {__float2bfloat16(v.x), __float2bfloat16(v.y),
               __float2bfloat16(v.z), __float2bfloat16(v.w)};
  *reinterpret_cast<ushort4*>(out + i) = *reinterpret_cast<const ushort4*>(o);
}

// two small weight tensors -> bf16 in one launch
__global__ void cvt_two(const float* __restrict__ a, bf16* __restrict__ oa, int na4,
                        const float* __restrict__ b, bf16* __restrict__ ob) {
  int t = blockIdx.x * 256 + threadIdx.x;
  const float* src;
  bf16* dst;
  size_t i;
  if (t < na4) {
    src = a; dst = oa; i = (size_t)t * 4;
  } else {
    src = b; dst = ob; i = (size_t)(t - na4) * 4;
  }
  float4 v = *reinterpret_cast<const float4*>(src + i);
  bf16 o[4] = {__float2bfloat16(v.x), __float2bfloat16(v.y),
               __float2bfloat16(v.z), __float2bfloat16(v.w)};
  *reinterpret_cast<ushort4*>(dst + i) = *reinterpret_cast<const ushort4*>(o);
}

// ---------------------------------------------------------------------------
// addend_p[w][h][q][c] (bf16), c = lg*16 + ki*4 + r  <->  k = ki*16 + lg*4 + r
// value = masked ? mask : table[pos_idx, h] ; k>=49 -> -1e30
// handles pos_idx stored as int32 OR int64 (odd-word-zero probe)
// ---------------------------------------------------------------------------
__global__ void build_addend(const float* __restrict__ mask, const int* __restrict__ pos,
                             const float* __restrict__ table, bf16* __restrict__ out) {
  int idx = blockIdx.x * 256 + threadIdx.x;   // total 64*12*49*64 = 2,408,448
  int c   = idx & 63;
  int rh  = idx >> 6;
  int row = rh % 49;
  int h   = (rh / 49) % 12;
  int w   = rh / (49 * 12);
  int k   = ((c >> 2) & 3) * 16 + (c >> 4) * 4 + (c & 3);
  float v = -1e30f;
  if (k < 49) {
    float m = mask[(w * 49 + row) * 49 + k];
    if (m != 0.0f) {
      v = m;
    } else {
      bool is64 = (pos[1] == 0) & (pos[3] == 0) & (pos[5] == 0) & (pos[7] == 0) &
                  (pos[9] == 0) & (pos[11] == 0) & (pos[13] == 0) & (pos[15] == 0);
      int pi = (w * 49 + row) * 49 + k;
      int p = is64 ? pos[2 * pi] : pos[pi];
      v = table[p * 12 + h];
    }
  }
  out[idx] = __float2bfloat16(v);
}

// ---------------------------------------------------------------------------
// GEMM: C[M,N] = A[M,K] @ B[N,K]^T + bias[N]   (A,B bf16 row-major K-contig)
// 128x128 tile, BK=32, 4 waves (2x2 of 64x64).
// A: global_load_lds staged (double-buffered).  B: L2-resident weights read
// DIRECTLY global->register, double-buffered (bf0/bf1) — halves LDS read
// traffic, which R7 counters showed at the ds_read_b128 ceiling (83 B/cy).
// K % 64 == 0 required (2x-unrolled K loop with named reg buffers).
// ---------------------------------------------------------------------------
template <bool OUT_BF16>
__global__ __launch_bounds__(256) void gemm_bt(
    const bf16* __restrict__ A, const bf16* __restrict__ Bm,
    const float* __restrict__ bias, void* __restrict__ Cout,
    int M, int N, int K, int nbn, int nwg) {
  __shared__ __align__(16) char smem_raw[17408];   // max(A dbuf 16KB, epilogue 16.9KB)
  bf16* As = (bf16*)smem_raw;                      // [2][128*32]
  const int t = threadIdx.x;
  const int lane = t & 63;
  const int w = t >> 6, wr = w >> 1, wc = w & 1;
  const int lid = xcd_swz(blockIdx.x, nwg);
  const int bm = lid / nbn, bn = lid % nbn;
  const int lr = lane & 15, lg = lane >> 4;

  const bf16* ag = A + ((size_t)(bm * 128 + (t >> 2))) * K + (t & 3) * 8;
  const size_t rstep = (size_t)64 * K;
  const int loff = t * 8;
  // per-wave B fragment base: row = bn*128 + wc*64 + j*16 + lr, cols lg*8..+8
  const bf16* bp = Bm + ((size_t)(bn * 128 + wc * 64 + lr)) * K + lg * 8;
  const size_t bj = (size_t)16 * K;

  f32x4 acc[4][4] = {};
  bf16x8 bf0[4], bf1[4];

  // prologue: stage A k-step 0 into buf0; load B frags k=0
  gload_lds16(ag, As + loff);
  gload_lds16(ag + rstep, As + loff + 64 * 32);
#pragma unroll
  for (int j = 0; j < 4; j++) bf0[j] = *reinterpret_cast<const bf16x8*>(bp + j * bj);
  __syncthreads();

  for (int k0 = 0; k0 < K; k0 += 64) {
    // ---- half 1: consume buf0/bf0; prefetch k0+32 -> buf1/bf1 ------------
    gload_lds16(ag + k0 + 32, As + 4096 + loff);
    gload_lds16(ag + k0 + 32 + rstep, As + 4096 + loff + 64 * 32);
#pragma unroll
    for (int j = 0; j < 4; j++)
      bf1[j] = *reinterpret_cast<const bf16x8*>(bp + j * bj + k0 + 32);
    {
      bf16x8 af[4];
      const bf16* ab = As + (wr * 64 + lr) * 32 + lg * 8;
#pragma unroll
      for (int i = 0; i < 4; i++) af[i] = *reinterpret_cast<const bf16x8*>(ab + i * 16 * 32);
#pragma unroll
      for (int i = 0; i < 4; i++)
#pragma unroll
        for (int j = 0; j < 4; j++)
          acc[i][j] = __builtin_amdgcn_mfma_f32_16x16x32_bf16(af[i], bf0[j], acc[i][j], 0, 0, 0);
    }
    __syncthreads();

    // ---- half 2: consume buf1/bf1; prefetch k0+64 -> buf0/bf0 ------------
    if (k0 + 64 < K) {
      gload_lds16(ag + k0 + 64, As + loff);
      gload_lds16(ag + k0 + 64 + rstep, As + loff + 64 * 32);
#pragma unroll
      for (int j = 0; j < 4; j++)
        bf0[j] = *reinterpret_cast<const bf16x8*>(bp + j * bj + k0 + 64);
    }
    {
      bf16x8 af[4];
      const bf16* ab = As + 4096 + (wr * 64 + lr) * 32 + lg * 8;
#pragma unroll
      for (int i = 0; i < 4; i++) af[i] = *reinterpret_cast<const bf16x8*>(ab + i * 16 * 32);
#pragma unroll
      for (int i = 0; i < 4; i++)
#pragma unroll
        for (int j = 0; j < 4; j++)
          acc[i][j] = __builtin_amdgcn_mfma_f32_16x16x32_bf16(af[i], bf1[j], acc[i][j], 0, 0, 0);
    }
    __syncthreads();
  }

  // ---- epilogue: LDS transpose -> coalesced dwordx4 stores ----------------
  float* ep = (float*)smem_raw + (size_t)w * 1056;   // 16*66 floats per wave
  const int erow = lane >> 3;        // 0..7
  const int ecol = (lane & 7) * 8;   // 0..56, 8 consecutive cols per lane
  const int gcol = bn * 128 + wc * 64 + ecol;
  float4 bv0 = *reinterpret_cast<const float4*>(&bias[gcol]);
  float4 bv1 = *reinterpret_cast<const float4*>(&bias[gcol + 4]);

#pragma unroll
  for (int i = 0; i < 4; i++) {
#pragma unroll
    for (int j = 0; j < 4; j++)
#pragma unroll
      for (int r = 0; r < 4; r++)
        ep[(lg * 4 + r) * 66 + j * 16 + lr] = acc[i][j][r];
    asm volatile("s_waitcnt lgkmcnt(0)" ::: "memory");  // wave-local RAW fence
#pragma unroll
    for (int p = 0; p < 2; p++) {
      int row = p * 8 + erow;
      float4 v0 = *reinterpret_cast<float4*>(&ep[row * 66 + ecol]);
      float4 v1 = *reinterpret_cast<float4*>(&ep[row * 66 + ecol + 4]);
      v0.x += bv0.x; v0.y += bv0.y; v0.z += bv0.z; v0.w += bv0.w;
      v1.x += bv1.x; v1.y += bv1.y; v1.z += bv1.z; v1.w += bv1.w;
      size_t goff = (size_t)(bm * 128 + wr * 64 + i * 16 + row) * N + gcol;
      if (OUT_BF16) {
        bf16 o[8] = {__float2bfloat16(v0.x), __float2bfloat16(v0.y),
                     __float2bfloat16(v0.z), __float2bfloat16(v0.w),
                     __float2bfloat16(v1.x), __float2bfloat16(v1.y),
                     __float2bfloat16(v1.z), __float2bfloat16(v1.w)};
        *reinterpret_cast<bf16x8*>((bf16*)Cout + goff) = *reinterpret_cast<const bf16x8*>(o);
      } else {
        *reinterpret_cast<float4*>((float*)Cout + goff) = v0;
        *reinterpret_cast<float4*>((float*)Cout + goff + 4) = v1;
      }
    }
    asm volatile("s_waitcnt lgkmcnt(0)" ::: "memory");  // reads done before next i writes
  }
}

// ---------------------------------------------------------------------------
// fused window attention: 1 wave per (b_, h). 49x49 scores padded to 64x64.
// qkv layout: [50176][1152] bf16, cols [0,384)=Q, [384,768)=K, [768,1152)=V.
// S^T = mfma(K,Q): lane holds P[q=qj*16+lr][k=ki*16+lg*4+r] -> that IS the
// A-fragment of mfma_f32_16x16x16_bf16, so PV runs from registers (no P LDS).
// addend is bf16, lane-permuted so each lane's 16 k-values are 32 contig bytes.
// ---------------------------------------------------------------------------
__global__ __launch_bounds__(64) void attn_kernel(
    const bf16* __restrict__ qkv, const bf16* __restrict__ addend,
    bf16* __restrict__ attn_out) {
  const int bid = xcd_swz(blockIdx.x, 12288);   // 12 consecutive bids share a window
  const int b = bid / 12;
  const int h = bid % 12;
  const int w = b & 63;
  const int lane = threadIdx.x;
  const int lr = lane & 15, lg = lane >> 4;
  const float scale = 0.17677669529663687f;  // 32^-0.5

  __shared__ ushort vT[32][72];     // V^T[d][k]

  const size_t base = (size_t)b * 49 * 1152;

  // --- Q, K fragments straight from global (rows >= 49 clamped to 48)
  bf16x8 qf[4], kf[4];
#pragma unroll
  for (int i = 0; i < 4; i++) {
    int rw = i * 16 + lr;
    int row = rw < 49 ? rw : 48;
    qf[i] = *reinterpret_cast<const bf16x8*>(qkv + base + (size_t)row * 1152 + h * 32 + lg * 8);
    kf[i] = *reinterpret_cast<const bf16x8*>(qkv + base + (size_t)row * 1152 + 384 + h * 32 + lg * 8);
  }

  // --- stage V transposed into LDS: vT[d][k] = V[k][d]; pad k>=49 with 0
  if (lane < 49) {
#pragma unroll
    for (int c4 = 0; c4 < 4; c4++) {
      bf16x8 vv = *reinterpret_cast<const bf16x8*>(
          qkv + base + (size_t)lane * 1152 + 768 + h * 32 + c4 * 8);
#pragma unroll
      for (int cc = 0; cc < 8; cc++) vT[c4 * 8 + cc][lane] = (ushort)vv[cc];
    }
  } else {
#pragma unroll
    for (int c = 0; c < 32; c++) vT[c][lane] = 0;
  }

  // --- per q-tile: S^T column, softmax over lane-local k, pack A-frags
  const bf16* add_base = addend + (size_t)(w * 12 + h) * 49 * 64;
  bf16x4 pa[4][4];   // [qj][ki]
#pragma unroll
  for (int qj = 0; qj < 4; qj++) {
    f32x4 s[4] = {};
    __builtin_amdgcn_s_setprio(1);
#pragma unroll
    for (int ki = 0; ki < 4; ki++)
      s[ki] = __builtin_amdgcn_mfma_f32_16x16x32_bf16(kf[ki], qf[qj], s[ki], 0, 0, 0);
    __builtin_amdgcn_s_setprio(0);

    int q = qj * 16 + lr;
    int qc = q < 49 ? q : 48;
    // lane's 16 addend values: contiguous 32 B at [qc][lg*16]
    const ushort* ap_ = (const ushort*)(add_base + (size_t)qc * 64 + lg * 16);
    bf16x8 a0 = *reinterpret_cast<const bf16x8*>(ap_);
    bf16x8 a1 = *reinterpret_cast<const bf16x8*>(ap_ + 8);
    float v[16];
    float mx = -1e38f;
#pragma unroll
    for (int u = 0; u < 8; u++) {
      v[u] = s[u >> 2][u & 3] * scale + b2f((ushort)a0[u]);
      v[u + 8] = s[(u >> 2) + 2][u & 3] * scale + b2f((ushort)a1[u]);
    }
#pragma unroll
    for (int u = 0; u < 16; u++) mx = fmaxf(mx, v[u]);
    mx = fmaxf(mx, __shfl_xor(mx, 16, 64));
    mx = fmaxf(mx, __shfl_xor(mx, 32, 64));
    float sum = 0.f;
#pragma unroll
    for (int u = 0; u < 16; u++) {
      v[u] = __expf(v[u] - mx);
      sum += v[u];
    }
    sum += __shfl_xor(sum, 16, 64);
    sum += __shfl_xor(sum, 32, 64);
    float rs = 1.0f / sum;
#pragma unroll
    for (int ki = 0; ki < 4; ki++) {
      bf16x4 p;
#pragma unroll
      for (int r = 0; r < 4; r++)
        p[r] = (short)__bfloat16_as_ushort(__float2bfloat16(v[ki * 4 + r] * rs));
      pa[qj][ki] = p;
    }
  }
  __syncthreads();   // vT ready

  // --- O = P @ V via 16x16x16: A=pa (in regs), B=V frag from vT
  f32x4 acc2[4][2] = {};
#pragma unroll
  for (int dt = 0; dt < 2; dt++) {
    bf16x4 vb[4];
#pragma unroll
    for (int ki = 0; ki < 4; ki++)
      vb[ki] = *reinterpret_cast<const bf16x4*>(&vT[dt * 16 + lr][ki * 16 + lg * 4]);
    __builtin_amdgcn_s_setprio(1);
#pragma unroll
    for (int qj = 0; qj < 4; qj++)
#pragma unroll
      for (int ki = 0; ki < 4; ki++)
        acc2[qj][dt] = mfma16(pa[qj][ki], vb[ki], acc2[qj][dt]);
    __builtin_amdgcn_s_setprio(0);
  }

  // --- store attn_out (bf16); P was pre-normalized
#pragma unroll
  for (int qj = 0; qj < 4; qj++)
#pragma unroll
    for (int r = 0; r < 4; r++) {
      int row = qj * 16 + lg * 4 + r;
      if (row < 49) {
#pragma unroll
        for (int dt = 0; dt < 2; dt++) {
          int col = h * 32 + dt * 16 + lr;
          attn_out[((size_t)b * 49 + row) * 384 + col] = __float2bfloat16(acc2[qj][dt][r]);
        }
      }
    }
}

// ---------------------------------------------------------------------------
// launch
// ---------------------------------------------------------------------------
extern "C" void kernel_launch(void* const* d_in, const int* in_sizes, int n_in,
                              void* d_out, int out_size, void* d_ws, size_t ws_size,
                              hipStream_t stream) {
  const float* x      = (const float*)d_in[0];
  const float* mask   = (const float*)d_in[1];
  const int*   posidx = (const int*)d_in[2];
  const float* table  = (const float*)d_in[3];
  const float* w_qkv  = (const float*)d_in[4];
  const float* b_qkv  = (const float*)d_in[5];
  const float* w_proj = (const float*)d_in[6];
  const float* b_proj = (const float*)d_in[7];
  float* out = (float*)d_out;

  char* ws = (char*)d_ws;
  bf16*  xb     = (bf16*)(ws + 0);            // 50176*384   bf16 = 38,535,168 B
  bf16*  wqkvb  = (bf16*)(ws + 38535168);     // 1152*384    bf16 =    884,736 B
  bf16*  wprojb = (bf16*)(ws + 39419904);     // 384*384     bf16 =    294,912 B
  bf16*  qkv    = (bf16*)(ws + 39714816);     // 50176*1152  bf16 = 115,605,504 B
  bf16*  aout   = (bf16*)(ws + 155320320);    // 50176*384   bf16 = 38,535,168 B
  bf16*  addend = (bf16*)(ws + 193855488);    // 64*12*49*64 bf16 =  4,816,896 B

  // conversions
  cvt_f32_bf16<<<18816, 256, 0, stream>>>(x, xb);                       // 19,267,584 elems
  cvt_two<<<576, 256, 0, stream>>>(w_qkv, wqkvb, 110592, w_proj, wprojb);

  // fused bias+mask addend table (bf16, lane-permuted)
  build_addend<<<9408, 256, 0, stream>>>(mask, posidx, table, addend);

  // qkv = x @ w_qkv^T + b_qkv   (M=50176, N=1152, K=384)
  gemm_bt<true><<<392 * 9, 256, 0, stream>>>(xb, wqkvb, b_qkv, qkv,
                                             50176, 1152, 384, 9, 392 * 9);

  // attention per (window-batch, head)
  attn_kernel<<<12288, 64, 0, stream>>>(qkv, addend, aout);

  // out = attn_out @ w_proj^T + b_proj   (M=50176, N=384, K=384)
  gemm_bt<false><<<392 * 3, 256, 0, stream>>>(aout, wprojb, b_proj, out,
                                              50176, 384, 384, 3, 392 * 3);
}

// Round 9
// 206.695 us; speedup vs baseline: 1.2380x; 1.2380x over previous
//
#include <hip/hip_runtime.h>
#include <hip/hip_bf16.h>

typedef __hip_bfloat16 bf16;
typedef __attribute__((ext_vector_type(4))) float f32x4;
typedef __attribute__((ext_vector_type(8))) short bf16x8;  // 8 bf16 in 4 VGPRs
typedef __attribute__((ext_vector_type(4))) short bf16x4;  // 4 bf16 in 2 VGPRs

// ---------------------------------------------------------------------------
// helpers
// ---------------------------------------------------------------------------
__device__ __forceinline__ void gload_lds16(const bf16* g, bf16* l) {
  __builtin_amdgcn_global_load_lds(
      (const __attribute__((address_space(1))) unsigned int*)(const void*)g,
      (__attribute__((address_space(3))) unsigned int*)(void*)l,
      16, 0, 0);
}

// XCD-contiguous bijective swizzle; REQUIRES nwg % 8 == 0.
__device__ __forceinline__ int xcd_swz(int orig, int nwg) {
  return (orig & 7) * (nwg >> 3) + (orig >> 3);
}

__device__ __forceinline__ float b2f(ushort u) {
  return __uint_as_float(((unsigned)u) << 16);
}

// 16x16x16 bf16 MFMA (K=16): A-frag = lane{row=l&15, k=(l>>4)*4+0..3}
#if defined(__has_builtin)
#if __has_builtin(__builtin_amdgcn_mfma_f32_16x16x16bf16_1k)
#define HAVE_MFMA16_BUILTIN 1
#endif
#endif
__device__ __forceinline__ f32x4 mfma16(bf16x4 a, bf16x4 b, f32x4 c) {
#ifdef HAVE_MFMA16_BUILTIN
  return __builtin_amdgcn_mfma_f32_16x16x16bf16_1k(a, b, c, 0, 0, 0);
#else
  asm("v_mfma_f32_16x16x16_bf16 %0, %1, %2, %0" : "+v"(c) : "v"(a), "v"(b));
  return c;
#endif
}

// ---------------------------------------------------------------------------
// two small weight tensors -> bf16 in one launch
// ---------------------------------------------------------------------------
__global__ void cvt_two(const float* __restrict__ a, bf16* __restrict__ oa, int na4,
                        const float* __restrict__ b, bf16* __restrict__ ob) {
  int t = blockIdx.x * 256 + threadIdx.x;
  const float* src;
  bf16* dst;
  size_t i;
  if (t < na4) {
    src = a; dst = oa; i = (size_t)t * 4;
  } else {
    src = b; dst = ob; i = (size_t)(t - na4) * 4;
  }
  float4 v = *reinterpret_cast<const float4*>(src + i);
  bf16 o[4] = {__float2bfloat16(v.x), __float2bfloat16(v.y),
               __float2bfloat16(v.z), __float2bfloat16(v.w)};
  *reinterpret_cast<ushort4*>(dst + i) = *reinterpret_cast<const ushort4*>(o);
}

// ---------------------------------------------------------------------------
// addend_p[w][h][q][c] (bf16), c = lg*16 + ki*4 + r  <->  k = ki*16 + lg*4 + r
// value = masked ? mask : table[pos_idx, h] ; k>=49 -> -1e30
// handles pos_idx stored as int32 OR int64 (odd-word-zero probe)
// ---------------------------------------------------------------------------
__global__ void build_addend(const float* __restrict__ mask, const int* __restrict__ pos,
                             const float* __restrict__ table, bf16* __restrict__ out) {
  int idx = blockIdx.x * 256 + threadIdx.x;   // total 64*12*49*64 = 2,408,448
  int c   = idx & 63;
  int rh  = idx >> 6;
  int row = rh % 49;
  int h   = (rh / 49) % 12;
  int w   = rh / (49 * 12);
  int k   = ((c >> 2) & 3) * 16 + (c >> 4) * 4 + (c & 3);
  float v = -1e30f;
  if (k < 49) {
    float m = mask[(w * 49 + row) * 49 + k];
    if (m != 0.0f) {
      v = m;
    } else {
      bool is64 = (pos[1] == 0) & (pos[3] == 0) & (pos[5] == 0) & (pos[7] == 0) &
                  (pos[9] == 0) & (pos[11] == 0) & (pos[13] == 0) & (pos[15] == 0);
      int pi = (w * 49 + row) * 49 + k;
      int p = is64 ? pos[2 * pi] : pos[pi];
      v = table[p * 12 + h];
    }
  }
  out[idx] = __float2bfloat16(v);
}

// ---------------------------------------------------------------------------
// GEMM: C[M,N] = A[M,K] @ B[N,K]^T + bias[N]
// 128x128 tile, BK=32, 4 waves (2x2 of 64x64), 2-phase dbuf pipeline
// (STAGE next -> compute cur -> one barrier) — R6 structure, best measured.
// A_F32: A is fp32; staged global->reg->cvt->ds_write with the loads issued
// BEFORE the MFMAs (T14 split: HBM latency hides under compute; the cvt+write
// lands after compute via register dependency). Eliminates the standalone
// x->bf16 conversion kernel. B always via global_load_lds.
// ---------------------------------------------------------------------------
template <bool OUT_BF16, bool A_F32>
__global__ __launch_bounds__(256) void gemm_bt(
    const void* __restrict__ Ain, const bf16* __restrict__ Bm,
    const float* __restrict__ bias, void* __restrict__ Cout,
    int M, int N, int K, int nbn, int nwg) {
  __shared__ bf16 As[2][128 * 32];
  __shared__ bf16 Bs[2][128 * 32];
  const int t = threadIdx.x;
  const int lane = t & 63;
  const int w = t >> 6, wr = w >> 1, wc = w & 1;
  const int lid = xcd_swz(blockIdx.x, nwg);
  const int bm = lid / nbn, bn = lid % nbn;
  const int lr = lane & 15, lg = lane >> 4;

  const bf16* bg = Bm + ((size_t)(bn * 128 + (t >> 2))) * K + (t & 3) * 8;
  const size_t rstep = (size_t)64 * K;
  const int loff = t * 8;

  const bf16*  ag  = nullptr;
  const float* agf = nullptr;
  if (A_F32)
    agf = (const float*)Ain + ((size_t)(bm * 128 + (t >> 2))) * K + (t & 3) * 8;
  else
    ag = (const bf16*)Ain + ((size_t)(bm * 128 + (t >> 2))) * K + (t & 3) * 8;

  f32x4 acc[4][4] = {};

  // prologue: stage K-step 0 into buffer 0
  if (A_F32) {
    float4 a00 = *reinterpret_cast<const float4*>(agf);
    float4 a01 = *reinterpret_cast<const float4*>(agf + 4);
    float4 a10 = *reinterpret_cast<const float4*>(agf + rstep);
    float4 a11 = *reinterpret_cast<const float4*>(agf + rstep + 4);
    gload_lds16(bg, Bs[0] + loff);
    gload_lds16(bg + rstep, Bs[0] + loff + 64 * 32);
    bf16 p0[8] = {__float2bfloat16(a00.x), __float2bfloat16(a00.y),
                  __float2bfloat16(a00.z), __float2bfloat16(a00.w),
                  __float2bfloat16(a01.x), __float2bfloat16(a01.y),
                  __float2bfloat16(a01.z), __float2bfloat16(a01.w)};
    bf16 p1[8] = {__float2bfloat16(a10.x), __float2bfloat16(a10.y),
                  __float2bfloat16(a10.z), __float2bfloat16(a10.w),
                  __float2bfloat16(a11.x), __float2bfloat16(a11.y),
                  __float2bfloat16(a11.z), __float2bfloat16(a11.w)};
    *reinterpret_cast<bf16x8*>(As[0] + loff) = *reinterpret_cast<const bf16x8*>(p0);
    *reinterpret_cast<bf16x8*>(As[0] + loff + 64 * 32) = *reinterpret_cast<const bf16x8*>(p1);
  } else {
    gload_lds16(ag, As[0] + loff);
    gload_lds16(ag + rstep, As[0] + loff + 64 * 32);
    gload_lds16(bg, Bs[0] + loff);
    gload_lds16(bg + rstep, Bs[0] + loff + 64 * 32);
  }
  __syncthreads();

  int cur = 0;
  for (int k0 = 0; k0 < K; k0 += 32) {
    const int nxt = cur ^ 1;
    const bool have_next = (k0 + 32 < K);

    float4 n00, n01, n10, n11;
    if (have_next) {
      if (A_F32) {
        // issue next A loads NOW (f32); consumed after the MFMAs below
        n00 = *reinterpret_cast<const float4*>(agf + k0 + 32);
        n01 = *reinterpret_cast<const float4*>(agf + k0 + 36);
        n10 = *reinterpret_cast<const float4*>(agf + k0 + 32 + rstep);
        n11 = *reinterpret_cast<const float4*>(agf + k0 + 36 + rstep);
      } else {
        gload_lds16(ag + k0 + 32, As[nxt] + loff);
        gload_lds16(ag + k0 + 32 + rstep, As[nxt] + loff + 64 * 32);
      }
      gload_lds16(bg + k0 + 32, Bs[nxt] + loff);
      gload_lds16(bg + k0 + 32 + rstep, Bs[nxt] + loff + 64 * 32);
    }

    bf16x8 af[4], bff[4];
    const bf16* ab = As[cur] + (wr * 64 + lr) * 32 + lg * 8;
    const bf16* bb = Bs[cur] + (wc * 64 + lr) * 32 + lg * 8;
#pragma unroll
    for (int i = 0; i < 4; i++) af[i] = *reinterpret_cast<const bf16x8*>(ab + i * 16 * 32);
#pragma unroll
    for (int j = 0; j < 4; j++) bff[j] = *reinterpret_cast<const bf16x8*>(bb + j * 16 * 32);
#pragma unroll
    for (int i = 0; i < 4; i++)
#pragma unroll
      for (int j = 0; j < 4; j++)
        acc[i][j] = __builtin_amdgcn_mfma_f32_16x16x32_bf16(af[i], bff[j], acc[i][j], 0, 0, 0);

    if (A_F32 && have_next) {
      // cvt + write into the buffer nobody reads this step (As[nxt])
      bf16 p0[8] = {__float2bfloat16(n00.x), __float2bfloat16(n00.y),
                    __float2bfloat16(n00.z), __float2bfloat16(n00.w),
                    __float2bfloat16(n01.x), __float2bfloat16(n01.y),
                    __float2bfloat16(n01.z), __float2bfloat16(n01.w)};
      bf16 p1[8] = {__float2bfloat16(n10.x), __float2bfloat16(n10.y),
                    __float2bfloat16(n10.z), __float2bfloat16(n10.w),
                    __float2bfloat16(n11.x), __float2bfloat16(n11.y),
                    __float2bfloat16(n11.z), __float2bfloat16(n11.w)};
      *reinterpret_cast<bf16x8*>(As[nxt] + loff) = *reinterpret_cast<const bf16x8*>(p0);
      *reinterpret_cast<bf16x8*>(As[nxt] + loff + 64 * 32) = *reinterpret_cast<const bf16x8*>(p1);
    }
    __syncthreads();   // drains prefetch vmcnt + lgkm; both buffers consistent
    cur = nxt;
  }

#pragma unroll
  for (int i = 0; i < 4; i++) {
    int row0 = bm * 128 + wr * 64 + i * 16 + lg * 4;
#pragma unroll
    for (int j = 0; j < 4; j++) {
      int col = bn * 128 + wc * 64 + j * 16 + lr;
      float bv = bias[col];
#pragma unroll
      for (int r = 0; r < 4; r++) {
        float v = acc[i][j][r] + bv;
        if (OUT_BF16)
          ((bf16*)Cout)[(size_t)(row0 + r) * N + col] = __float2bfloat16(v);
        else
          ((float*)Cout)[(size_t)(row0 + r) * N + col] = v;
      }
    }
  }
}

// ---------------------------------------------------------------------------
// fused window attention: 1 wave per (b_, h). 49x49 scores padded to 64x64.
// qkv layout: [50176][1152] bf16, cols [0,384)=Q, [384,768)=K, [768,1152)=V.
// S^T = mfma(K,Q): lane holds P[q=qj*16+lr][k=ki*16+lg*4+r] -> that IS the
// A-fragment of mfma_f32_16x16x16_bf16, so PV runs from registers (no P LDS).
// addend is bf16, lane-permuted so each lane's 16 k-values are 32 contig bytes.
// ---------------------------------------------------------------------------
__global__ __launch_bounds__(64) void attn_kernel(
    const bf16* __restrict__ qkv, const bf16* __restrict__ addend,
    bf16* __restrict__ attn_out) {
  const int bid = xcd_swz(blockIdx.x, 12288);   // 12 consecutive bids share a window
  const int b = bid / 12;
  const int h = bid % 12;
  const int w = b & 63;
  const int lane = threadIdx.x;
  const int lr = lane & 15, lg = lane >> 4;
  const float scale = 0.17677669529663687f;  // 32^-0.5

  __shared__ ushort vT[32][72];     // V^T[d][k]

  const size_t base = (size_t)b * 49 * 1152;

  // --- Q, K fragments straight from global (rows >= 49 clamped to 48)
  bf16x8 qf[4], kf[4];
#pragma unroll
  for (int i = 0; i < 4; i++) {
    int rw = i * 16 + lr;
    int row = rw < 49 ? rw : 48;
    qf[i] = *reinterpret_cast<const bf16x8*>(qkv + base + (size_t)row * 1152 + h * 32 + lg * 8);
    kf[i] = *reinterpret_cast<const bf16x8*>(qkv + base + (size_t)row * 1152 + 384 + h * 32 + lg * 8);
  }

  // --- stage V transposed into LDS: vT[d][k] = V[k][d]; pad k>=49 with 0
  if (lane < 49) {
#pragma unroll
    for (int c4 = 0; c4 < 4; c4++) {
      bf16x8 vv = *reinterpret_cast<const bf16x8*>(
          qkv + base + (size_t)lane * 1152 + 768 + h * 32 + c4 * 8);
#pragma unroll
      for (int cc = 0; cc < 8; cc++) vT[c4 * 8 + cc][lane] = (ushort)vv[cc];
    }
  } else {
#pragma unroll
    for (int c = 0; c < 32; c++) vT[c][lane] = 0;
  }

  // --- per q-tile: S^T column, softmax over lane-local k, pack A-frags
  const bf16* add_base = addend + (size_t)(w * 12 + h) * 49 * 64;
  bf16x4 pa[4][4];   // [qj][ki]
#pragma unroll
  for (int qj = 0; qj < 4; qj++) {
    f32x4 s[4] = {};
    __builtin_amdgcn_s_setprio(1);
#pragma unroll
    for (int ki = 0; ki < 4; ki++)
      s[ki] = __builtin_amdgcn_mfma_f32_16x16x32_bf16(kf[ki], qf[qj], s[ki], 0, 0, 0);
    __builtin_amdgcn_s_setprio(0);

    int q = qj * 16 + lr;
    int qc = q < 49 ? q : 48;
    // lane's 16 addend values: contiguous 32 B at [qc][lg*16]
    const ushort* ap_ = (const ushort*)(add_base + (size_t)qc * 64 + lg * 16);
    bf16x8 a0 = *reinterpret_cast<const bf16x8*>(ap_);
    bf16x8 a1 = *reinterpret_cast<const bf16x8*>(ap_ + 8);
    float v[16];
    float mx = -1e38f;
#pragma unroll
    for (int u = 0; u < 8; u++) {
      v[u] = s[u >> 2][u & 3] * scale + b2f((ushort)a0[u]);
      v[u + 8] = s[(u >> 2) + 2][u & 3] * scale + b2f((ushort)a1[u]);
    }
#pragma unroll
    for (int u = 0; u < 16; u++) mx = fmaxf(mx, v[u]);
    mx = fmaxf(mx, __shfl_xor(mx, 16, 64));
    mx = fmaxf(mx, __shfl_xor(mx, 32, 64));
    float sum = 0.f;
#pragma unroll
    for (int u = 0; u < 16; u++) {
      v[u] = __expf(v[u] - mx);
      sum += v[u];
    }
    sum += __shfl_xor(sum, 16, 64);
    sum += __shfl_xor(sum, 32, 64);
    float rs = 1.0f / sum;
#pragma unroll
    for (int ki = 0; ki < 4; ki++) {
      bf16x4 p;
#pragma unroll
      for (int r = 0; r < 4; r++)
        p[r] = (short)__bfloat16_as_ushort(__float2bfloat16(v[ki * 4 + r] * rs));
      pa[qj][ki] = p;
    }
  }
  __syncthreads();   // vT ready

  // --- O = P @ V via 16x16x16: A=pa (in regs), B=V frag from vT
  f32x4 acc2[4][2] = {};
#pragma unroll
  for (int dt = 0; dt < 2; dt++) {
    bf16x4 vb[4];
#pragma unroll
    for (int ki = 0; ki < 4; ki++)
      vb[ki] = *reinterpret_cast<const bf16x4*>(&vT[dt * 16 + lr][ki * 16 + lg * 4]);
    __builtin_amdgcn_s_setprio(1);
#pragma unroll
    for (int qj = 0; qj < 4; qj++)
#pragma unroll
      for (int ki = 0; ki < 4; ki++)
        acc2[qj][dt] = mfma16(pa[qj][ki], vb[ki], acc2[qj][dt]);
    __builtin_amdgcn_s_setprio(0);
  }

  // --- store attn_out (bf16); P was pre-normalized
#pragma unroll
  for (int qj = 0; qj < 4; qj++)
#pragma unroll
    for (int r = 0; r < 4; r++) {
      int row = qj * 16 + lg * 4 + r;
      if (row < 49) {
#pragma unroll
        for (int dt = 0; dt < 2; dt++) {
          int col = h * 32 + dt * 16 + lr;
          attn_out[((size_t)b * 49 + row) * 384 + col] = __float2bfloat16(acc2[qj][dt][r]);
        }
      }
    }
}

// ---------------------------------------------------------------------------
// launch
// ---------------------------------------------------------------------------
extern "C" void kernel_launch(void* const* d_in, const int* in_sizes, int n_in,
                              void* d_out, int out_size, void* d_ws, size_t ws_size,
                              hipStream_t stream) {
  const float* x      = (const float*)d_in[0];
  const float* mask   = (const float*)d_in[1];
  const int*   posidx = (const int*)d_in[2];
  const float* table  = (const float*)d_in[3];
  const float* w_qkv  = (const float*)d_in[4];
  const float* b_qkv  = (const float*)d_in[5];
  const float* w_proj = (const float*)d_in[6];
  const float* b_proj = (const float*)d_in[7];
  float* out = (float*)d_out;

  char* ws = (char*)d_ws;
  bf16*  wqkvb  = (bf16*)(ws + 0);            // 1152*384    bf16 =    884,736 B
  bf16*  wprojb = (bf16*)(ws + 884736);       // 384*384     bf16 =    294,912 B
  bf16*  qkv    = (bf16*)(ws + 1179648);      // 50176*1152  bf16 = 115,605,504 B
  bf16*  aout   = (bf16*)(ws + 116785152);    // 50176*384   bf16 = 38,535,168 B
  bf16*  addend = (bf16*)(ws + 155320320);    // 64*12*49*64 bf16 =  4,816,896 B

  // weight conversions (one small launch)
  cvt_two<<<576, 256, 0, stream>>>(w_qkv, wqkvb, 110592, w_proj, wprojb);

  // fused bias+mask addend table (bf16, lane-permuted)
  build_addend<<<9408, 256, 0, stream>>>(mask, posidx, table, addend);

  // qkv = x @ w_qkv^T + b_qkv   (M=50176, N=1152, K=384); x f32, cvt fused
  gemm_bt<true, true><<<392 * 9, 256, 0, stream>>>(x, wqkvb, b_qkv, qkv,
                                                   50176, 1152, 384, 9, 392 * 9);

  // attention per (window-batch, head)
  attn_kernel<<<12288, 64, 0, stream>>>(qkv, addend, aout);

  // out = attn_out @ w_proj^T + b_proj   (M=50176, N=384, K=384)
  gemm_bt<false, false><<<392 * 3, 256, 0, stream>>>(aout, wprojb, b_proj, out,
                                                     50176, 384, 384, 3, 392 * 3);
}

// Round 10
// 175.250 us; speedup vs baseline: 1.4601x; 1.1794x over previous
//
#include <hip/hip_runtime.h>
#include <hip/hip_bf16.h>

typedef __hip_bfloat16 bf16;
typedef __attribute__((ext_vector_type(4))) float f32x4;
typedef __attribute__((ext_vector_type(8))) short bf16x8;  // 8 bf16 in 4 VGPRs
typedef __attribute__((ext_vector_type(4))) short bf16x4;  // 4 bf16 in 2 VGPRs

// ---------------------------------------------------------------------------
// helpers
// ---------------------------------------------------------------------------
__device__ __forceinline__ void gload_lds16(const bf16* g, bf16* l) {
  __builtin_amdgcn_global_load_lds(
      (const __attribute__((address_space(1))) unsigned int*)(const void*)g,
      (__attribute__((address_space(3))) unsigned int*)(void*)l,
      16, 0, 0);
}

// XCD-contiguous bijective swizzle; REQUIRES nwg % 8 == 0.
__device__ __forceinline__ int xcd_swz(int orig, int nwg) {
  return (orig & 7) * (nwg >> 3) + (orig >> 3);
}

__device__ __forceinline__ float b2f(ushort u) {
  return __uint_as_float(((unsigned)u) << 16);
}

// 16x16x16 bf16 MFMA (K=16): A-frag = lane{row=l&15, k=(l>>4)*4+0..3}
#if defined(__has_builtin)
#if __has_builtin(__builtin_amdgcn_mfma_f32_16x16x16bf16_1k)
#define HAVE_MFMA16_BUILTIN 1
#endif
#endif
__device__ __forceinline__ f32x4 mfma16(bf16x4 a, bf16x4 b, f32x4 c) {
#ifdef HAVE_MFMA16_BUILTIN
  return __builtin_amdgcn_mfma_f32_16x16x16bf16_1k(a, b, c, 0, 0, 0);
#else
  asm("v_mfma_f32_16x16x16_bf16 %0, %1, %2, %0" : "+v"(c) : "v"(a), "v"(b));
  return c;
#endif
}

// ---------------------------------------------------------------------------
// fp32 -> bf16 conversion (vectorized, exact grid)
// ---------------------------------------------------------------------------
__global__ void cvt_f32_bf16(const float* __restrict__ in, bf16* __restrict__ out) {
  size_t i = ((size_t)blockIdx.x * 256 + threadIdx.x) * 4;
  float4 v = *reinterpret_cast<const float4*>(in + i);
  bf16 o[4] = {__float2bfloat16(v.x), __float2bfloat16(v.y),
               __float2bfloat16(v.z), __float2bfloat16(v.w)};
  *reinterpret_cast<ushort4*>(out + i) = *reinterpret_cast<const ushort4*>(o);
}

// two small weight tensors -> bf16 in one launch
__global__ void cvt_two(const float* __restrict__ a, bf16* __restrict__ oa, int na4,
                        const float* __restrict__ b, bf16* __restrict__ ob) {
  int t = blockIdx.x * 256 + threadIdx.x;
  const float* src;
  bf16* dst;
  size_t i;
  if (t < na4) {
    src = a; dst = oa; i = (size_t)t * 4;
  } else {
    src = b; dst = ob; i = (size_t)(t - na4) * 4;
  }
  float4 v = *reinterpret_cast<const float4*>(src + i);
  bf16 o[4] = {__float2bfloat16(v.x), __float2bfloat16(v.y),
               __float2bfloat16(v.z), __float2bfloat16(v.w)};
  *reinterpret_cast<ushort4*>(dst + i) = *reinterpret_cast<const ushort4*>(o);
}

// ---------------------------------------------------------------------------
// addend_p[w][h][q][c] (bf16), c = lg*16 + ki*4 + r  <->  k = ki*16 + lg*4 + r
// value = masked ? mask : table[pos_idx, h] ; k>=49 -> -1e30
// handles pos_idx stored as int32 OR int64 (odd-word-zero probe)
// ---------------------------------------------------------------------------
__global__ void build_addend(const float* __restrict__ mask, const int* __restrict__ pos,
                             const float* __restrict__ table, bf16* __restrict__ out) {
  int idx = blockIdx.x * 256 + threadIdx.x;   // total 64*12*49*64 = 2,408,448
  int c   = idx & 63;
  int rh  = idx >> 6;
  int row = rh % 49;
  int h   = (rh / 49) % 12;
  int w   = rh / (49 * 12);
  int k   = ((c >> 2) & 3) * 16 + (c >> 4) * 4 + (c & 3);
  float v = -1e30f;
  if (k < 49) {
    float m = mask[(w * 49 + row) * 49 + k];
    if (m != 0.0f) {
      v = m;
    } else {
      bool is64 = (pos[1] == 0) & (pos[3] == 0) & (pos[5] == 0) & (pos[7] == 0) &
                  (pos[9] == 0) & (pos[11] == 0) & (pos[13] == 0) & (pos[15] == 0);
      int pi = (w * 49 + row) * 49 + k;
      int p = is64 ? pos[2 * pi] : pos[pi];
      v = table[p * 12 + h];
    }
  }
  out[idx] = __float2bfloat16(v);
}

// ---------------------------------------------------------------------------
// GEMM: C[M,N] = A[M,K] @ B[N,K]^T + bias[N]   (A,B bf16 row-major K-contig)
// 128x128 tile, BK=32, 4 waves (2x2 of 64x64), global_load_lds width 16.
// 3-buffer, 2-deep prefetch with COUNTED vmcnt (T4): raw s_barrier + explicit
// s_waitcnt vmcnt(4) so the next tile's 4 loads stay in flight across the
// barrier (never drain to 0 in the main loop). __syncthreads would emit
// vmcnt(0) and stall every K-step on the just-issued prefetch.
// Buffer safety: live tiles k,k+1,k+2 are distinct mod 3; buf[k] is only
// re-written by stage(k+3), issued after barrier k+1, by which point every
// wave's iter-k ds_reads have completed (lgkm dep before last MFMA).
// ---------------------------------------------------------------------------
template <bool OUT_BF16>
__global__ __launch_bounds__(256) void gemm_bt(
    const bf16* __restrict__ A, const bf16* __restrict__ Bm,
    const float* __restrict__ bias, void* __restrict__ Cout,
    int M, int N, int K, int nbn, int nwg) {
  __shared__ bf16 As[3 * 128 * 32];
  __shared__ bf16 Bs[3 * 128 * 32];
  const int t = threadIdx.x;
  const int lane = t & 63;
  const int w = t >> 6, wr = w >> 1, wc = w & 1;
  const int lid = xcd_swz(blockIdx.x, nwg);
  const int bm = lid / nbn, bn = lid % nbn;
  const int lr = lane & 15, lg = lane >> 4;

  const bf16* ag = A + ((size_t)(bm * 128 + (t >> 2))) * K + (t & 3) * 8;
  const bf16* bg = Bm + ((size_t)(bn * 128 + (t >> 2))) * K + (t & 3) * 8;
  const size_t rstep = (size_t)64 * K;
  const int loff = t * 8;

  // stage tile tt (K-cols tt*32..+32) into buffer tt%3: 4 gload_lds per thread
  auto stage = [&](int tt) {
    const int bi = tt % 3;
    bf16* ad = As + bi * 4096 + loff;
    bf16* bd = Bs + bi * 4096 + loff;
    const bf16* as_ = ag + tt * 32;
    const bf16* bs_ = bg + tt * 32;
    gload_lds16(as_, ad);
    gload_lds16(as_ + rstep, ad + 2048);
    gload_lds16(bs_, bd);
    gload_lds16(bs_ + rstep, bd + 2048);
  };

  f32x4 acc[4][4] = {};
  const int nt = K >> 5;   // K=384 -> 12 tiles; nt >= 2 assumed

  stage(0);
  stage(1);

  for (int kt = 0; kt < nt; ++kt) {
    // wait only for the OLDEST tile's 4 loads; keep the next tile in flight
    if (kt + 1 < nt)
      asm volatile("s_waitcnt vmcnt(4)" ::: "memory");
    else
      asm volatile("s_waitcnt vmcnt(0)" ::: "memory");
    __builtin_amdgcn_s_barrier();
    if (kt + 2 < nt) stage(kt + 2);

    const int bi = kt % 3;
    bf16x8 af[4], bff[4];
    const bf16* ab = As + bi * 4096 + (wr * 64 + lr) * 32 + lg * 8;
    const bf16* bb = Bs + bi * 4096 + (wc * 64 + lr) * 32 + lg * 8;
#pragma unroll
    for (int i = 0; i < 4; i++) af[i] = *reinterpret_cast<const bf16x8*>(ab + i * 16 * 32);
#pragma unroll
    for (int j = 0; j < 4; j++) bff[j] = *reinterpret_cast<const bf16x8*>(bb + j * 16 * 32);
#pragma unroll
    for (int i = 0; i < 4; i++)
#pragma unroll
      for (int j = 0; j < 4; j++)
        acc[i][j] = __builtin_amdgcn_mfma_f32_16x16x32_bf16(af[i], bff[j], acc[i][j], 0, 0, 0);
  }

#pragma unroll
  for (int i = 0; i < 4; i++) {
    int row0 = bm * 128 + wr * 64 + i * 16 + lg * 4;
#pragma unroll
    for (int j = 0; j < 4; j++) {
      int col = bn * 128 + wc * 64 + j * 16 + lr;
      float bv = bias[col];
#pragma unroll
      for (int r = 0; r < 4; r++) {
        float v = acc[i][j][r] + bv;
        if (OUT_BF16)
          ((bf16*)Cout)[(size_t)(row0 + r) * N + col] = __float2bfloat16(v);
        else
          ((float*)Cout)[(size_t)(row0 + r) * N + col] = v;
      }
    }
  }
}

// ---------------------------------------------------------------------------
// fused window attention: 1 wave per (b_, h). 49x49 scores padded to 64x64.
// qkv layout: [50176][1152] bf16, cols [0,384)=Q, [384,768)=K, [768,1152)=V.
// S^T = mfma(K,Q): lane holds P[q=qj*16+lr][k=ki*16+lg*4+r] -> that IS the
// A-fragment of mfma_f32_16x16x16_bf16, so PV runs from registers (no P LDS).
// addend is bf16, lane-permuted so each lane's 16 k-values are 32 contig bytes.
// ---------------------------------------------------------------------------
__global__ __launch_bounds__(64) void attn_kernel(
    const bf16* __restrict__ qkv, const bf16* __restrict__ addend,
    bf16* __restrict__ attn_out) {
  const int bid = xcd_swz(blockIdx.x, 12288);   // 12 consecutive bids share a window
  const int b = bid / 12;
  const int h = bid % 12;
  const int w = b & 63;
  const int lane = threadIdx.x;
  const int lr = lane & 15, lg = lane >> 4;
  const float scale = 0.17677669529663687f;  // 32^-0.5

  __shared__ ushort vT[32][72];     // V^T[d][k]

  const size_t base = (size_t)b * 49 * 1152;

  // --- Q, K fragments straight from global (rows >= 49 clamped to 48)
  bf16x8 qf[4], kf[4];
#pragma unroll
  for (int i = 0; i < 4; i++) {
    int rw = i * 16 + lr;
    int row = rw < 49 ? rw : 48;
    qf[i] = *reinterpret_cast<const bf16x8*>(qkv + base + (size_t)row * 1152 + h * 32 + lg * 8);
    kf[i] = *reinterpret_cast<const bf16x8*>(qkv + base + (size_t)row * 1152 + 384 + h * 32 + lg * 8);
  }

  // --- stage V transposed into LDS: vT[d][k] = V[k][d]; pad k>=49 with 0
  if (lane < 49) {
#pragma unroll
    for (int c4 = 0; c4 < 4; c4++) {
      bf16x8 vv = *reinterpret_cast<const bf16x8*>(
          qkv + base + (size_t)lane * 1152 + 768 + h * 32 + c4 * 8);
#pragma unroll
      for (int cc = 0; cc < 8; cc++) vT[c4 * 8 + cc][lane] = (ushort)vv[cc];
    }
  } else {
#pragma unroll
    for (int c = 0; c < 32; c++) vT[c][lane] = 0;
  }

  // --- per q-tile: S^T column, softmax over lane-local k, pack A-frags
  const bf16* add_base = addend + (size_t)(w * 12 + h) * 49 * 64;
  bf16x4 pa[4][4];   // [qj][ki]
#pragma unroll
  for (int qj = 0; qj < 4; qj++) {
    f32x4 s[4] = {};
    __builtin_amdgcn_s_setprio(1);
#pragma unroll
    for (int ki = 0; ki < 4; ki++)
      s[ki] = __builtin_amdgcn_mfma_f32_16x16x32_bf16(kf[ki], qf[qj], s[ki], 0, 0, 0);
    __builtin_amdgcn_s_setprio(0);

    int q = qj * 16 + lr;
    int qc = q < 49 ? q : 48;
    // lane's 16 addend values: contiguous 32 B at [qc][lg*16]
    const ushort* ap_ = (const ushort*)(add_base + (size_t)qc * 64 + lg * 16);
    bf16x8 a0 = *reinterpret_cast<const bf16x8*>(ap_);
    bf16x8 a1 = *reinterpret_cast<const bf16x8*>(ap_ + 8);
    float v[16];
    float mx = -1e38f;
#pragma unroll
    for (int u = 0; u < 8; u++) {
      v[u] = s[u >> 2][u & 3] * scale + b2f((ushort)a0[u]);
      v[u + 8] = s[(u >> 2) + 2][u & 3] * scale + b2f((ushort)a1[u]);
    }
#pragma unroll
    for (int u = 0; u < 16; u++) mx = fmaxf(mx, v[u]);
    mx = fmaxf(mx, __shfl_xor(mx, 16, 64));
    mx = fmaxf(mx, __shfl_xor(mx, 32, 64));
    float sum = 0.f;
#pragma unroll
    for (int u = 0; u < 16; u++) {
      v[u] = __expf(v[u] - mx);
      sum += v[u];
    }
    sum += __shfl_xor(sum, 16, 64);
    sum += __shfl_xor(sum, 32, 64);
    float rs = 1.0f / sum;
#pragma unroll
    for (int ki = 0; ki < 4; ki++) {
      bf16x4 p;
#pragma unroll
      for (int r = 0; r < 4; r++)
        p[r] = (short)__bfloat16_as_ushort(__float2bfloat16(v[ki * 4 + r] * rs));
      pa[qj][ki] = p;
    }
  }
  __syncthreads();   // vT ready

  // --- O = P @ V via 16x16x16: A=pa (in regs), B=V frag from vT
  f32x4 acc2[4][2] = {};
#pragma unroll
  for (int dt = 0; dt < 2; dt++) {
    bf16x4 vb[4];
#pragma unroll
    for (int ki = 0; ki < 4; ki++)
      vb[ki] = *reinterpret_cast<const bf16x4*>(&vT[dt * 16 + lr][ki * 16 + lg * 4]);
    __builtin_amdgcn_s_setprio(1);
#pragma unroll
    for (int qj = 0; qj < 4; qj++)
#pragma unroll
      for (int ki = 0; ki < 4; ki++)
        acc2[qj][dt] = mfma16(pa[qj][ki], vb[ki], acc2[qj][dt]);
    __builtin_amdgcn_s_setprio(0);
  }

  // --- store attn_out (bf16); P was pre-normalized
#pragma unroll
  for (int qj = 0; qj < 4; qj++)
#pragma unroll
    for (int r = 0; r < 4; r++) {
      int row = qj * 16 + lg * 4 + r;
      if (row < 49) {
#pragma unroll
        for (int dt = 0; dt < 2; dt++) {
          int col = h * 32 + dt * 16 + lr;
          attn_out[((size_t)b * 49 + row) * 384 + col] = __float2bfloat16(acc2[qj][dt][r]);
        }
      }
    }
}

// ---------------------------------------------------------------------------
// launch
// ---------------------------------------------------------------------------
extern "C" void kernel_launch(void* const* d_in, const int* in_sizes, int n_in,
                              void* d_out, int out_size, void* d_ws, size_t ws_size,
                              hipStream_t stream) {
  const float* x      = (const float*)d_in[0];
  const float* mask   = (const float*)d_in[1];
  const int*   posidx = (const int*)d_in[2];
  const float* table  = (const float*)d_in[3];
  const float* w_qkv  = (const float*)d_in[4];
  const float* b_qkv  = (const float*)d_in[5];
  const float* w_proj = (const float*)d_in[6];
  const float* b_proj = (const float*)d_in[7];
  float* out = (float*)d_out;

  char* ws = (char*)d_ws;
  bf16*  xb     = (bf16*)(ws + 0);            // 50176*384   bf16 = 38,535,168 B
  bf16*  wqkvb  = (bf16*)(ws + 38535168);     // 1152*384    bf16 =    884,736 B
  bf16*  wprojb = (bf16*)(ws + 39419904);     // 384*384     bf16 =    294,912 B
  bf16*  qkv    = (bf16*)(ws + 39714816);     // 50176*1152  bf16 = 115,605,504 B
  bf16*  aout   = (bf16*)(ws + 155320320);    // 50176*384   bf16 = 38,535,168 B
  bf16*  addend = (bf16*)(ws + 193855488);    // 64*12*49*64 bf16 =  4,816,896 B

  // conversions
  cvt_f32_bf16<<<18816, 256, 0, stream>>>(x, xb);                       // 19,267,584 elems
  cvt_two<<<576, 256, 0, stream>>>(w_qkv, wqkvb, 110592, w_proj, wprojb);

  // fused bias+mask addend table (bf16, lane-permuted)
  build_addend<<<9408, 256, 0, stream>>>(mask, posidx, table, addend);

  // qkv = x @ w_qkv^T + b_qkv   (M=50176, N=1152, K=384)
  gemm_bt<true><<<392 * 9, 256, 0, stream>>>(xb, wqkvb, b_qkv, qkv,
                                             50176, 1152, 384, 9, 392 * 9);

  // attention per (window-batch, head)
  attn_kernel<<<12288, 64, 0, stream>>>(qkv, addend, aout);

  // out = attn_out @ w_proj^T + b_proj   (M=50176, N=384, K=384)
  gemm_bt<false><<<392 * 3, 256, 0, stream>>>(aout, wprojb, b_proj, out,
                                              50176, 384, 384, 3, 392 * 3);
}